// Round 11
// baseline (43.478 us; speedup 1.0000x reference)
//
#include <hip/hip_runtime.h>

namespace {

constexpr int T   = 16384;
constexpr int B   = 8;
constexpr int C4  = 64;              // 256 fp32 channels = 64 float4
constexpr int SUB = 8;               // outputs per wave
constexpr int WAVES = 4;             // block = 256 threads
constexpr int BLOCK_T = SUB * WAVES; // 32 outputs per block
constexpr int ROWS = BLOCK_T + 10;   // 42 staged rows (halo 5 each side)
constexpr int CHUNKS = T / BLOCK_T;  // 512 chunks per batch
constexpr int ROW_B = C4 * 16;       // 1024 bytes per row
constexpr int NBLK  = B * CHUNKS;    // 4096 blocks
constexpr int NXCD  = 8;
constexpr int CPX   = NBLK / NXCD;   // 512 — exact, bijective swizzle

typedef __attribute__((address_space(3))) void lds_void;
typedef const __attribute__((address_space(1))) void gbl_void;

__global__ __launch_bounds__(256) void runavg_kernel(const float4* __restrict__ x,
                                                     float4* __restrict__ out) {
    __shared__ float4 lds[ROWS * C4];   // 43008 B -> 3 blocks/CU

    const int tid  = threadIdx.x;
    const int lane = tid & 63;
    const int wid  = tid >> 6;

    // XCD-chunked bijective swizzle (T1): each XCD owns one contiguous
    // batch-span -> neighbor-chunk halo re-reads hit own-XCD L2.
    const int bid  = blockIdx.x;
    const int work = (bid % NXCD) * CPX + bid / NXCD;

    const int b   = work / CHUNKS;
    const int t0b = (work % CHUNKS) * BLOCK_T;

    const bool first = (t0b == 0);
    const bool last  = (t0b + BLOCK_T == T);
    const bool guard = first || last;

    // ---- stage 42 rows into LDS; iteration `it` stages row r = it*4+wid ----
    // LDS dest is wave-uniform base (+ lane*16 by HW); global src per-lane.
    const float* xf = (const float*)x;
    #pragma unroll
    for (int it = 0; it < 11; ++it) {
        const int r = it * 4 + wid;
        if (r < ROWS) {
            const int t = t0b - 5 + r;
            if (!guard || ((unsigned)t < (unsigned)T)) {   // skip OOB rows (zeroed below)
                const float* gp = xf + ((size_t)b * T + t) * 256 + lane * 4;
                __builtin_amdgcn_global_load_lds((gbl_void*)gp,
                                                 (lds_void*)((char*)lds + r * ROW_B),
                                                 16, 0, 0);
            }
        }
    }

    // zero the skipped out-of-range rows (guard blocks only; block-uniform branch)
    if (guard) {
        const float4 z = make_float4(0.f, 0.f, 0.f, 0.f);
        for (int u = tid; u < 5 * C4; u += 256) {
            const int rr = u >> 6, cc = u & 63;
            if (first) lds[rr * C4 + cc] = z;                 // rows 0..4  (t = -5..-1)
            if (last)  lds[(ROWS - 5 + rr) * C4 + cc] = z;    // rows 37..41 (t = T..T+4)
        }
    }
    __syncthreads();   // drains global_load_lds (vmcnt) + ds_writes

    // ---- compute: register-load this wave's 18-row window from LDS ----
    constexpr float INV = 1.0f / 11.0f;
    const int t0 = t0b + wid * SUB;
    float4 r[SUB + 10];
    #pragma unroll
    for (int i = 0; i < SUB + 10; ++i) {
        r[i] = lds[(wid * SUB + i) * C4 + lane];   // ds_read_b128, conflict-free stripe
    }
    __builtin_amdgcn_sched_barrier(0);

    float4* ob = out + ((size_t)b * T + t0) * C4 + lane;

    float4 s = {0.f, 0.f, 0.f, 0.f};
    #pragma unroll
    for (int i = 0; i < 11; ++i) {
        s.x += r[i].x; s.y += r[i].y; s.z += r[i].z; s.w += r[i].w;
    }
    float4 o;
    o.x = s.x * INV; o.y = s.y * INV; o.z = s.z * INV; o.w = s.w * INV;
    ob[0] = o;                                   // regular store (lazy writeback)

    #pragma unroll
    for (int i = 1; i < SUB; ++i) {
        const float4 a = r[i + 10];
        const float4 d = r[i - 1];
        s.x += a.x - d.x; s.y += a.y - d.y; s.z += a.z - d.z; s.w += a.w - d.w;
        o.x = s.x * INV; o.y = s.y * INV; o.z = s.z * INV; o.w = s.w * INV;
        ob[(size_t)i * C4] = o;
    }
}

} // namespace

extern "C" void kernel_launch(void* const* d_in, const int* in_sizes, int n_in,
                              void* d_out, int out_size, void* d_ws, size_t ws_size,
                              hipStream_t stream) {
    const float4* x = (const float4*)d_in[0];
    float4* out = (float4*)d_out;
    runavg_kernel<<<NBLK, 256, 0, stream>>>(x, out);
}